// Round 3
// baseline (158.307 us; speedup 1.0000x reference)
//
#include <hip/hip_runtime.h>
#include <hip/hip_bf16.h>

#define N_NODES 4096
#define IN_F 512
#define HEADS 8
#define HPH 8
#define HID 64
#define CLS 16
#define NEG_SLOPE 0.2f
#define MAXD 256   // max neighbors stored per node (Poisson(~17): P(>256) ~ 0)

__device__ __forceinline__ float leaky(float x) { return x > 0.f ? x : NEG_SLOPE * x; }

// ---------------- Kernel 1: g1 = x @ W1, sl1/sr1 scores -------------------
// grid 4096 blocks x 64 threads; thread c = h*8+d owns one output column.
__global__ void proj1(const float* __restrict__ x,
                      const float* __restrict__ W1,
                      const float* __restrict__ a1l,
                      const float* __restrict__ a1r,
                      float* __restrict__ g1,
                      float* __restrict__ sl1,
                      float* __restrict__ sr1) {
    const int i = blockIdx.x;
    const int c = threadIdx.x;  // 0..63
    __shared__ float xs[IN_F];
    const float4* xr = (const float4*)(x + (size_t)i * IN_F);
    for (int k = c; k < IN_F / 4; k += 64) ((float4*)xs)[k] = xr[k];
    __syncthreads();
    float acc = 0.f;
#pragma unroll 8
    for (int k = 0; k < IN_F; ++k)
        acc += xs[k] * W1[k * HID + c];
    g1[(size_t)i * HID + c] = acc;
    float pl = acc * a1l[c];
    float pr = acc * a1r[c];
    // reduce over d within each 8-lane head group
#pragma unroll
    for (int off = 1; off < 8; off <<= 1) {
        pl += __shfl_xor(pl, off, 64);
        pr += __shfl_xor(pr, off, 64);
    }
    if ((c & 7) == 0) {
        sl1[i * HEADS + (c >> 3)] = pl;
        sr1[i * HEADS + (c >> 3)] = pr;
    }
}

// ---------------- Kernel 2: layer-1 attention + ELU -----------------------
// adj is int32 (jax bool widened by harness). One block per destination node.
// Persists compacted neighbor list to ws for reuse by attn2.
__global__ void attn1(const int* __restrict__ adj,
                      const float* __restrict__ g1,
                      const float* __restrict__ sl1,
                      const float* __restrict__ sr1,
                      float* __restrict__ h1,
                      int* __restrict__ deg_g,
                      int* __restrict__ nbr_g) {
    const int i = blockIdx.x;
    const int t = threadIdx.x;  // c = h*8+d
    __shared__ int nbr[MAXD];
    __shared__ int cnt;
    if (t == 0) cnt = 0;
    __syncthreads();
    const int4* row = (const int4*)(adj + (size_t)i * N_NODES);
    for (int w = t; w < N_NODES / 4; w += 64) {
        int4 v = row[w];
        if (v.x | v.y | v.z | v.w) {
            if (v.x) { int p = atomicAdd(&cnt, 1); if (p < MAXD) nbr[p] = 4 * w + 0; }
            if (v.y) { int p = atomicAdd(&cnt, 1); if (p < MAXD) nbr[p] = 4 * w + 1; }
            if (v.z) { int p = atomicAdd(&cnt, 1); if (p < MAXD) nbr[p] = 4 * w + 2; }
            if (v.w) { int p = atomicAdd(&cnt, 1); if (p < MAXD) nbr[p] = 4 * w + 3; }
        }
    }
    __syncthreads();
    const int n = cnt < MAXD ? cnt : MAXD;
    if (t == 0) deg_g[i] = n;
    for (int k = t; k < n; k += 64) nbr_g[(size_t)i * MAXD + k] = nbr[k];

    const int h = t >> 3;
    const float sl = sl1[i * HEADS + h];
    float mx = -1e30f;
    for (int k = 0; k < n; ++k)
        mx = fmaxf(mx, sr1[nbr[k] * HEADS + h]);
    const float m = leaky(sl + mx);  // leaky monotone: max of leaky = leaky of max
    float denom = 0.f, acc = 0.f;
    for (int k = 0; k < n; ++k) {
        const int jj = nbr[k];
        const float e = leaky(sl + sr1[jj * HEADS + h]);
        const float w = __expf(e - m);
        denom += w;
        acc += w * g1[(size_t)jj * HID + t];
    }
    float o = (n > 0) ? (acc / denom) : 0.f;
    h1[(size_t)i * HID + t] = (o > 0.f) ? o : expm1f(o);  // ELU
}

// ---------------- Kernel 3: g2 = h1 @ W2, sl2/sr2 -------------------------
__global__ void proj2(const float* __restrict__ h1,
                      const float* __restrict__ W2,
                      const float* __restrict__ a2l,
                      const float* __restrict__ a2r,
                      float* __restrict__ g2,
                      float* __restrict__ sl2,
                      float* __restrict__ sr2) {
    const int t = threadIdx.x;         // 0..255
    const int node = blockIdx.x * 16 + (t >> 4);
    const int c = t & 15;
    __shared__ float w2s[HID * CLS];
    for (int k = t; k < HID * CLS; k += 256) w2s[k] = W2[k];
    __syncthreads();
    const float* hr = h1 + (size_t)node * HID;
    float acc = 0.f;
#pragma unroll
    for (int k = 0; k < HID; ++k) acc += hr[k] * w2s[k * CLS + c];
    g2[(size_t)node * CLS + c] = acc;
    float pl = acc * a2l[c];
    float pr = acc * a2r[c];
#pragma unroll
    for (int off = 1; off < 16; off <<= 1) {
        pl += __shfl_xor(pl, off, 64);
        pr += __shfl_xor(pr, off, 64);
    }
    if (c == 0) { sl2[node] = pl; sr2[node] = pr; }
}

// ---------------- Kernel 4: layer-2 attention -> fp32 out -----------------
__global__ void attn2(const int* __restrict__ deg_g,
                      const int* __restrict__ nbr_g,
                      const float* __restrict__ g2,
                      const float* __restrict__ sl2,
                      const float* __restrict__ sr2,
                      float* __restrict__ out) {
    const int i = blockIdx.x;
    const int t = threadIdx.x;  // 64
    __shared__ int nbr[MAXD];
    const int n = deg_g[i];
    for (int k = t; k < n; k += 64) nbr[k] = nbr_g[(size_t)i * MAXD + k];
    __syncthreads();
    const float sl = sl2[i];
    float mx = -1e30f;
    for (int k = 0; k < n; ++k)
        mx = fmaxf(mx, sr2[nbr[k]]);
    const float m = leaky(sl + mx);
    float denom = 0.f, acc = 0.f;
    for (int k = 0; k < n; ++k) {
        const int jj = nbr[k];
        const float w = __expf(leaky(sl + sr2[jj]) - m);
        denom += w;
        if (t < CLS) acc += w * g2[(size_t)jj * CLS + t];
    }
    if (t < CLS) out[(size_t)i * CLS + t] = (n > 0) ? acc / denom : 0.f;
}

extern "C" void kernel_launch(void* const* d_in, const int* in_sizes, int n_in,
                              void* d_out, int out_size, void* d_ws, size_t ws_size,
                              hipStream_t stream) {
    const float* x   = (const float*)d_in[0];
    const int*   adj = (const int*)d_in[1];
    const float* W1  = (const float*)d_in[2];
    const float* a1l = (const float*)d_in[3];
    const float* a1r = (const float*)d_in[4];
    const float* W2  = (const float*)d_in[5];
    const float* a2l = (const float*)d_in[6];
    const float* a2r = (const float*)d_in[7];
    float* out = (float*)d_out;

    float* ws  = (float*)d_ws;
    float* g1  = ws;                                  // 4096*64
    float* sl1 = g1  + (size_t)N_NODES * HID;         // 4096*8
    float* sr1 = sl1 + (size_t)N_NODES * HEADS;
    float* h1  = sr1 + (size_t)N_NODES * HEADS;       // 4096*64
    float* g2  = h1  + (size_t)N_NODES * HID;         // 4096*16
    float* sl2 = g2  + (size_t)N_NODES * CLS;         // 4096
    float* sr2 = sl2 + N_NODES;
    int*   deg = (int*)(sr2 + N_NODES);               // 4096
    int*   nbr = deg + N_NODES;                       // 4096*MAXD (4 MB)

    proj1<<<N_NODES, 64, 0, stream>>>(x, W1, a1l, a1r, g1, sl1, sr1);
    attn1<<<N_NODES, 64, 0, stream>>>(adj, g1, sl1, sr1, h1, deg, nbr);
    proj2<<<N_NODES / 16, 256, 0, stream>>>(h1, W2, a2l, a2r, g2, sl2, sr2);
    attn2<<<N_NODES, 64, 0, stream>>>(deg, nbr, g2, sl2, sr2, out);
}

// Round 4
// 151.764 us; speedup vs baseline: 1.0431x; 1.0431x over previous
//
#include <hip/hip_runtime.h>
#include <hip/hip_bf16.h>

#define N_NODES 4096
#define IN_F 512
#define HEADS 8
#define HPH 8
#define HID 64
#define CLS 16
#define NEG_SLOPE 0.2f
#define MAXD 256   // max neighbors stored per node (Poisson(~17): P(>256) ~ 0)

__device__ __forceinline__ float leaky(float x) { return x > 0.f ? x : NEG_SLOPE * x; }

// ---------------- Kernel 1: g1 = x @ W1, sl1/sr1 scores -------------------
// 256 blocks x 256 threads; block = 16 nodes, thread = (node, 4 cols).
// Register-tiled: float4 W1 loads, ds_read_b128 x reads.
__global__ void proj1(const float* __restrict__ x,
                      const float* __restrict__ W1,
                      const float* __restrict__ a1l,
                      const float* __restrict__ a1r,
                      float* __restrict__ g1,
                      float* __restrict__ sl1,
                      float* __restrict__ sr1) {
    const int t  = threadIdx.x;          // 0..255
    const int nl = t >> 4;               // node within block (0..15)
    const int c4 = (t & 15) * 4;         // first of 4 output cols
    const int i0 = blockIdx.x * 16;
    __shared__ float xs[16][516];        // +4 pad: rows 4 banks apart, b128 ranges disjoint
    {   // stage 16 x-rows, 16 threads per row, float4
        const int row = nl;
        const float4* src = (const float4*)(x + (size_t)(i0 + row) * IN_F);
        float4* dst = (float4*)(&xs[row][0]);
        for (int k = (t & 15); k < IN_F / 4; k += 16) dst[k] = src[k];
    }
    __syncthreads();
    float4 acc = make_float4(0.f, 0.f, 0.f, 0.f);
    const float* xrow = &xs[nl][0];
#pragma unroll 4
    for (int k = 0; k < IN_F; k += 4) {
        const float4 xv = *(const float4*)(xrow + k);
        const float4 w0 = *(const float4*)(W1 + (size_t)(k + 0) * HID + c4);
        const float4 w1 = *(const float4*)(W1 + (size_t)(k + 1) * HID + c4);
        const float4 w2 = *(const float4*)(W1 + (size_t)(k + 2) * HID + c4);
        const float4 w3 = *(const float4*)(W1 + (size_t)(k + 3) * HID + c4);
        acc.x += xv.x * w0.x + xv.y * w1.x + xv.z * w2.x + xv.w * w3.x;
        acc.y += xv.x * w0.y + xv.y * w1.y + xv.z * w2.y + xv.w * w3.y;
        acc.z += xv.x * w0.z + xv.y * w1.z + xv.z * w2.z + xv.w * w3.z;
        acc.w += xv.x * w0.w + xv.y * w1.w + xv.z * w2.w + xv.w * w3.w;
    }
    const int i = i0 + nl;
    *(float4*)(g1 + (size_t)i * HID + c4) = acc;
    const float4 al = *(const float4*)(a1l + c4);
    const float4 ar = *(const float4*)(a1r + c4);
    float pl = acc.x * al.x + acc.y * al.y + acc.z * al.z + acc.w * al.w;
    float pr = acc.x * ar.x + acc.y * ar.y + acc.z * ar.z + acc.w * ar.w;
    // cols c4..c4+7 (thread pair t, t^1) form one head
    pl += __shfl_xor(pl, 1, 64);
    pr += __shfl_xor(pr, 1, 64);
    if ((t & 1) == 0) {
        const int h = (t & 15) >> 1;
        sl1[i * HEADS + h] = pl;
        sr1[i * HEADS + h] = pr;
    }
}

// ------ Kernel 2: layer-1 attention + ELU + proj2 (fused), saves nbr lists ---
// One block (64 threads) per destination node. No softmax max-pass: scores
// |leaky(sl+sr)| <~ 1.5 so exp() is safe unnormalized in fp32.
__global__ void attn1_fused(const int* __restrict__ adj,
                            const float* __restrict__ g1,
                            const float* __restrict__ sl1,
                            const float* __restrict__ sr1,
                            const float* __restrict__ W2,
                            const float* __restrict__ a2l,
                            const float* __restrict__ a2r,
                            float* __restrict__ g2,
                            float* __restrict__ sl2,
                            float* __restrict__ sr2,
                            int* __restrict__ deg_g,
                            int* __restrict__ nbr_g) {
    const int i = blockIdx.x;
    const int t = threadIdx.x;  // 0..63, c = h*8+d
    __shared__ int nbr[MAXD];
    __shared__ int cnt;
    __shared__ float h1s[HID];
    if (t == 0) cnt = 0;
    __syncthreads();
    const int4* row = (const int4*)(adj + (size_t)i * N_NODES);
    for (int w = t; w < N_NODES / 4; w += 64) {
        int4 v = row[w];
        if (v.x | v.y | v.z | v.w) {
            if (v.x) { int p = atomicAdd(&cnt, 1); if (p < MAXD) nbr[p] = 4 * w + 0; }
            if (v.y) { int p = atomicAdd(&cnt, 1); if (p < MAXD) nbr[p] = 4 * w + 1; }
            if (v.z) { int p = atomicAdd(&cnt, 1); if (p < MAXD) nbr[p] = 4 * w + 2; }
            if (v.w) { int p = atomicAdd(&cnt, 1); if (p < MAXD) nbr[p] = 4 * w + 3; }
        }
    }
    __syncthreads();
    const int n = cnt < MAXD ? cnt : MAXD;
    if (t == 0) deg_g[i] = n;
    for (int k = t; k < n; k += 64) nbr_g[(size_t)i * MAXD + k] = nbr[k];

    const int h = t >> 3;
    const float sl = sl1[i * HEADS + h];
    float denom = 0.f, acc = 0.f;
    for (int k = 0; k < n; ++k) {
        const int jj = nbr[k];
        const float w = __expf(leaky(sl + sr1[jj * HEADS + h]));
        denom += w;
        acc += w * g1[(size_t)jj * HID + t];
    }
    float o = (n > 0) ? (acc / denom) : 0.f;
    o = (o > 0.f) ? o : expm1f(o);            // ELU
    h1s[t] = o;
    __syncthreads();

    // proj2: g2[i][c] = sum_k h1s[k] * W2[k][c]; lane t = (quarter q, class c)
    const int q = t >> 4, c = t & 15;
    float p = 0.f;
#pragma unroll
    for (int kk = 0; kk < 16; ++kk) {
        const int k2 = q * 16 + kk;
        p += h1s[k2] * W2[k2 * CLS + c];
    }
    p += __shfl_xor(p, 16, 64);
    p += __shfl_xor(p, 32, 64);
    float pl = 0.f, pr = 0.f;
    if (t < CLS) {
        g2[(size_t)i * CLS + t] = p;
        pl = p * a2l[t];
        pr = p * a2r[t];
    }
#pragma unroll
    for (int off = 1; off < 16; off <<= 1) {
        pl += __shfl_xor(pl, off, 64);
        pr += __shfl_xor(pr, off, 64);
    }
    if (t == 0) { sl2[i] = pl; sr2[i] = pr; }
}

// ---------------- Kernel 3: layer-2 attention -> fp32 out -----------------
// 1024 blocks x 64 threads; 4 nodes per block, 16 lanes (classes) per node.
__global__ void attn2(const int* __restrict__ deg_g,
                      const int* __restrict__ nbr_g,
                      const float* __restrict__ g2,
                      const float* __restrict__ sl2,
                      const float* __restrict__ sr2,
                      float* __restrict__ out) {
    const int t = threadIdx.x;          // 0..63
    const int g = t >> 4;               // node group 0..3
    const int c = t & 15;               // class
    const int node = blockIdx.x * 4 + g;
    __shared__ int nbrs[4][MAXD];
    const int n = deg_g[node];
    for (int k = c; k < n; k += 16) nbrs[g][k] = nbr_g[(size_t)node * MAXD + k];
    __syncthreads();
    const float sl = sl2[node];
    float denom = 0.f, acc = 0.f;
    for (int k = 0; k < n; ++k) {
        const int jj = nbrs[g][k];
        const float w = __expf(leaky(sl + sr2[jj]));
        denom += w;
        acc += w * g2[(size_t)jj * CLS + c];
    }
    out[(size_t)node * CLS + c] = (n > 0) ? acc / denom : 0.f;
}

extern "C" void kernel_launch(void* const* d_in, const int* in_sizes, int n_in,
                              void* d_out, int out_size, void* d_ws, size_t ws_size,
                              hipStream_t stream) {
    const float* x   = (const float*)d_in[0];
    const int*   adj = (const int*)d_in[1];
    const float* W1  = (const float*)d_in[2];
    const float* a1l = (const float*)d_in[3];
    const float* a1r = (const float*)d_in[4];
    const float* W2  = (const float*)d_in[5];
    const float* a2l = (const float*)d_in[6];
    const float* a2r = (const float*)d_in[7];
    float* out = (float*)d_out;

    float* ws  = (float*)d_ws;
    float* g1  = ws;                                  // 4096*64
    float* sl1 = g1  + (size_t)N_NODES * HID;         // 4096*8
    float* sr1 = sl1 + (size_t)N_NODES * HEADS;
    float* g2  = sr1 + (size_t)N_NODES * HEADS;       // 4096*16
    float* sl2 = g2  + (size_t)N_NODES * CLS;         // 4096
    float* sr2 = sl2 + N_NODES;
    int*   deg = (int*)(sr2 + N_NODES);               // 4096
    int*   nbr = deg + N_NODES;                       // 4096*MAXD (4 MB)

    proj1<<<N_NODES / 16, 256, 0, stream>>>(x, W1, a1l, a1r, g1, sl1, sr1);
    attn1_fused<<<N_NODES, 64, 0, stream>>>(adj, g1, sl1, sr1, W2, a2l, a2r,
                                            g2, sl2, sr2, deg, nbr);
    attn2<<<N_NODES / 4, 64, 0, stream>>>(deg, nbr, g2, sl2, sr2, out);
}